// Round 5
// baseline (293.444 us; speedup 1.0000x reference)
//
#include <hip/hip_runtime.h>
#include <math.h>

#define FIN 128
#define NH 8
#define HC 128
#define HD (NH*HC)   // 1024
#define NC 18
#define NCP 24       // W2 row padded to 24 ch (48B, b128-aligned)
#define NEG 0.2f

typedef __attribute__((ext_vector_type(8))) short bf16x8;
typedef __attribute__((ext_vector_type(4))) float f32x4;

__device__ __forceinline__ float lrelu(float v){ return v > 0.f ? v : NEG*v; }

// round-to-nearest-even fp32 -> bf16
__device__ __forceinline__ unsigned short f2b(float f){
  unsigned u = __float_as_uint(f);
  unsigned r = (u + 0x7fffu + ((u >> 16) & 1u)) >> 16;
  return (unsigned short)r;
}
__device__ __forceinline__ float b2f_lo(unsigned u){ return __uint_as_float(u << 16); }
__device__ __forceinline__ float b2f_hi(unsigned u){ return __uint_as_float(u & 0xffff0000u); }

__device__ __forceinline__ void acc8(float* a, float w, uint4 r){
  a[0] += w*b2f_lo(r.x); a[1] += w*b2f_hi(r.x);
  a[2] += w*b2f_lo(r.y); a[3] += w*b2f_hi(r.y);
  a[4] += w*b2f_lo(r.z); a[5] += w*b2f_hi(r.z);
  a[6] += w*b2f_lo(r.w); a[7] += w*b2f_hi(r.w);
}

// ---------------- CSR build (by destination) ----------------
__global__ void hist_k(const int* __restrict__ ei, int E0, int N, int* __restrict__ deg){
  int e = blockIdx.x*256 + threadIdx.x;
  int tot = E0 + N;
  if (e >= tot) return;
  int dst = (e < E0) ? ei[E0 + e] : (e - E0);
  atomicAdd(&deg[dst], 1);
}

__global__ __launch_bounds__(1024) void scan_k(const int* __restrict__ deg, int N,
                                               int* __restrict__ off, int* __restrict__ cursor){
  __shared__ int wsum[16];
  __shared__ int s_carry;
  int t = threadIdx.x, lane = t & 63, wid = t >> 6;
  if (t == 0) s_carry = 0;
  __syncthreads();
  for (int base = 0; base < N; base += 1024) {
    int i = base + t;
    int v = (i < N) ? deg[i] : 0;
    int x = v;
    #pragma unroll
    for (int o = 1; o < 64; o <<= 1) {
      int y = __shfl_up(x, o, 64);
      if (lane >= o) x += y;
    }
    if (lane == 63) wsum[wid] = x;
    __syncthreads();
    if (wid == 0) {
      int wv = (lane < 16) ? wsum[lane] : 0;
      #pragma unroll
      for (int o = 1; o < 16; o <<= 1) {
        int y = __shfl_up(wv, o, 64);
        if (lane >= o) wv += y;
      }
      if (lane < 16) wsum[lane] = wv;
    }
    __syncthreads();
    int woff = (wid > 0) ? wsum[wid-1] : 0;
    int carry = s_carry;
    int exc = x - v + woff + carry;
    if (i < N) { off[i] = exc; cursor[i] = exc; }
    __syncthreads();
    if (t == 1023) s_carry = carry + wsum[15];
    __syncthreads();
  }
  if (t == 0) off[N] = s_carry;
}

__global__ void scatter_k(const int* __restrict__ ei, int E0, int N,
                          int* __restrict__ cursor, int* __restrict__ csr){
  int e = blockIdx.x*256 + threadIdx.x;
  int tot = E0 + N;
  if (e >= tot) return;
  int src, dst;
  if (e < E0) { src = ei[e]; dst = ei[E0 + e]; }
  else        { src = e - E0; dst = src; }
  int p = atomicAdd(&cursor[dst], 1);
  csr[p] = src;
}

// ---------------- converts ----------------
__global__ __launch_bounds__(256) void xcvt_k(const float* __restrict__ x,
                                              unsigned short* __restrict__ xb, int total8){
  int i = blockIdx.x*256 + threadIdx.x;
  if (i >= total8) return;
  const float4* p = (const float4*)x + (size_t)i*2;
  float4 a = p[0], b = p[1];
  uint4 o;
  o.x = (unsigned)f2b(a.x) | ((unsigned)f2b(a.y) << 16);
  o.y = (unsigned)f2b(a.z) | ((unsigned)f2b(a.w) << 16);
  o.z = (unsigned)f2b(b.x) | ((unsigned)f2b(b.y) << 16);
  o.w = (unsigned)f2b(b.z) | ((unsigned)f2b(b.w) << 16);
  ((uint4*)xb)[i] = o;
}

__global__ __launch_bounds__(256) void w1t_k(const float* __restrict__ W1,
                                             unsigned short* __restrict__ w1t){
  __shared__ unsigned short sT[FIN][64+2];
  int t = threadIdx.x;
  int n0 = blockIdx.x * 64;
  #pragma unroll
  for (int i = 0; i < 32; ++i) {
    int idx = i*256 + t;
    int k = idx >> 6, nl = idx & 63;
    sT[k][nl] = f2b(W1[(size_t)k*HD + n0 + nl]);
  }
  __syncthreads();
  #pragma unroll
  for (int i = 0; i < 16; ++i) {
    int nl = i*4 + (t >> 6);
    int kp = t & 63;
    unsigned u = (unsigned)sT[2*kp][nl] | ((unsigned)sT[2*kp+1][nl] << 16);
    *(unsigned*)&w1t[(size_t)(n0+nl)*FIN + 2*kp] = u;
  }
}

// W2 fp32 [1024][18] -> bf16 padded [1024][24]
__global__ __launch_bounds__(256) void w2cvt_k(const float* __restrict__ W2,
                                               unsigned short* __restrict__ w2b){
  int idx = blockIdx.x*256 + threadIdx.x;
  if (idx >= HD*NC) return;
  int k = idx / NC, c = idx - k*NC;
  w2b[k*NCP + c] = f2b(W2[idx]);
}

// ---------------- GEMM1 (MFMA bf16): g1b = bf16(xb @ w1t^T), K=128 ----------------
__global__ __launch_bounds__(256) void gemm1_mfma_k(const unsigned short* __restrict__ xb,
                                                    const unsigned short* __restrict__ w1t,
                                                    unsigned short* __restrict__ g1b, int N){
  __shared__ unsigned short sA[128][136];
  __shared__ unsigned short sB[128][136];
  int t = threadIdx.x, lane = t & 63, wid = t >> 6;
  int bm = blockIdx.x * 128;
  int bn = blockIdx.y * 128;
  #pragma unroll
  for (int i = 0; i < 2; ++i) {
    int idx = i*256 + t;
    int row = idx >> 2, seg = idx & 3;
    int gm = bm + row;
    uint4 a0,a1,a2,a3;
    if (gm < N) {
      const uint4* gp = (const uint4*)(xb + (size_t)gm*FIN + seg*32);
      a0 = gp[0]; a1 = gp[1]; a2 = gp[2]; a3 = gp[3];
    } else {
      a0 = a1 = a2 = a3 = make_uint4(0,0,0,0);
    }
    uint4* lp = (uint4*)&sA[row][seg*32];
    lp[0]=a0; lp[1]=a1; lp[2]=a2; lp[3]=a3;
  }
  #pragma unroll
  for (int i = 0; i < 2; ++i) {
    int idx = i*256 + t;
    int row = idx >> 2, seg = idx & 3;
    const uint4* gp = (const uint4*)(w1t + (size_t)(bn + row)*FIN + seg*32);
    uint4* lp = (uint4*)&sB[row][seg*32];
    lp[0]=gp[0]; lp[1]=gp[1]; lp[2]=gp[2]; lp[3]=gp[3];
  }
  __syncthreads();
  int wr = wid >> 1, wc = wid & 1;
  int lr = lane & 15, kb = lane >> 4;
  f32x4 acc[4][4];
  #pragma unroll
  for (int mi = 0; mi < 4; ++mi)
    #pragma unroll
    for (int ni = 0; ni < 4; ++ni) {
      f32x4 z = {0.f, 0.f, 0.f, 0.f};
      acc[mi][ni] = z;
    }
  #pragma unroll
  for (int ks = 0; ks < 4; ++ks) {
    int ko = ks*32 + kb*8;
    bf16x8 a[4], b[4];
    #pragma unroll
    for (int mi = 0; mi < 4; ++mi)
      a[mi] = *(const bf16x8*)&sA[wr*64 + mi*16 + lr][ko];
    #pragma unroll
    for (int ni = 0; ni < 4; ++ni)
      b[ni] = *(const bf16x8*)&sB[wc*64 + ni*16 + lr][ko];
    #pragma unroll
    for (int mi = 0; mi < 4; ++mi)
      #pragma unroll
      for (int ni = 0; ni < 4; ++ni)
        acc[mi][ni] = __builtin_amdgcn_mfma_f32_16x16x32_bf16(a[mi], b[ni], acc[mi][ni], 0, 0, 0);
  }
  #pragma unroll
  for (int mi = 0; mi < 4; ++mi)
    #pragma unroll
    for (int ni = 0; ni < 4; ++ni) {
      int col = bn + wc*64 + ni*16 + lr;
      #pragma unroll
      for (int r = 0; r < 4; ++r) {
        int row = bm + wr*64 + mi*16 + kb*4 + r;
        if (row < N) g1b[(size_t)row*HD + col] = f2b(acc[mi][ni][r]);
      }
    }
}

// ---------------- alpha1: wave-per-node logits ----------------
__global__ __launch_bounds__(256) void alpha1_k(const unsigned short* __restrict__ g1b,
    const float* __restrict__ a1s, const float* __restrict__ a1d,
    float* __restrict__ as1, float* __restrict__ ad1, int N){
  int t = threadIdx.x, lane = t & 63, wid = t >> 6;
  int n = blockIdx.x*4 + wid;
  if (n >= N) return;
  int c0 = lane * 16;
  int h = lane >> 3;
  const uint4* p = (const uint4*)(g1b + (size_t)n*HD) + lane*2;
  uint4 r0 = p[0], r1 = p[1];
  float hv[16];
  hv[0]=b2f_lo(r0.x); hv[1]=b2f_hi(r0.x); hv[2]=b2f_lo(r0.y); hv[3]=b2f_hi(r0.y);
  hv[4]=b2f_lo(r0.z); hv[5]=b2f_hi(r0.z); hv[6]=b2f_lo(r0.w); hv[7]=b2f_hi(r0.w);
  hv[8]=b2f_lo(r1.x); hv[9]=b2f_hi(r1.x); hv[10]=b2f_lo(r1.y); hv[11]=b2f_hi(r1.y);
  hv[12]=b2f_lo(r1.z); hv[13]=b2f_hi(r1.z); hv[14]=b2f_lo(r1.w); hv[15]=b2f_hi(r1.w);
  float s = 0.f, dd = 0.f;
  #pragma unroll
  for (int q = 0; q < 4; ++q) {
    float4 av = *(const float4*)&a1s[c0 + q*4];
    float4 bv = *(const float4*)&a1d[c0 + q*4];
    s  += hv[q*4+0]*av.x + hv[q*4+1]*av.y + hv[q*4+2]*av.z + hv[q*4+3]*av.w;
    dd += hv[q*4+0]*bv.x + hv[q*4+1]*bv.y + hv[q*4+2]*bv.z + hv[q*4+3]*bv.w;
  }
  #pragma unroll
  for (int o = 1; o < 8; o <<= 1) {
    s  += __shfl_xor(s, o, 8);
    dd += __shfl_xor(dd, o, 8);
  }
  if ((lane & 7) == 0) { as1[n*NH + h] = s; ad1[n*NH + h] = dd; }
}

// ---------------- attn1: wave-per-dst SINGLE-PASS online softmax + chunk-4 gather ----------------
__global__ __launch_bounds__(256) void attn1_k(const unsigned short* __restrict__ g1b,
    const float* __restrict__ as1, const float* __restrict__ ad1,
    const int* __restrict__ off, const int* __restrict__ csr,
    const float* __restrict__ b1, unsigned short* __restrict__ hb, int N){
  int t = threadIdx.x, lane = t & 63, wid = t >> 6;
  int d = blockIdx.x*4 + wid;
  if (d >= N) return;
  int beg = off[d], deg = off[d+1] - beg;
  int hg = lane >> 3;                 // head for this lane's 16 channels
  float adg = ad1[d*NH + hg];
  float m = -1e30f, z = 0.f;
  float acc[16];
  #pragma unroll
  for (int i = 0; i < 16; ++i) acc[i] = 0.f;

  int j = 0;
  for (; j + 4 <= deg; j += 4) {
    int s0 = csr[beg+j+0], s1 = csr[beg+j+1], s2 = csr[beg+j+2], s3 = csr[beg+j+3];
    const uint4* p0 = (const uint4*)(g1b + (size_t)s0*HD) + lane*2;
    const uint4* p1 = (const uint4*)(g1b + (size_t)s1*HD) + lane*2;
    const uint4* p2 = (const uint4*)(g1b + (size_t)s2*HD) + lane*2;
    const uint4* p3 = (const uint4*)(g1b + (size_t)s3*HD) + lane*2;
    uint4 r00 = p0[0], r01 = p0[1];
    uint4 r10 = p1[0], r11 = p1[1];
    uint4 r20 = p2[0], r21 = p2[1];
    uint4 r30 = p3[0], r31 = p3[1];
    float e0 = lrelu(as1[s0*NH+hg] + adg);
    float e1 = lrelu(as1[s1*NH+hg] + adg);
    float e2 = lrelu(as1[s2*NH+hg] + adg);
    float e3 = lrelu(as1[s3*NH+hg] + adg);
    float em = fmaxf(fmaxf(e0,e1), fmaxf(e2,e3));
    if (em > m) {
      float sc = __expf(m - em);
      z *= sc;
      #pragma unroll
      for (int i = 0; i < 16; ++i) acc[i] *= sc;
      m = em;
    }
    float w0 = __expf(e0 - m), w1 = __expf(e1 - m);
    float w2 = __expf(e2 - m), w3 = __expf(e3 - m);
    z += w0 + w1 + w2 + w3;
    acc8(acc, w0, r00); acc8(acc+8, w0, r01);
    acc8(acc, w1, r10); acc8(acc+8, w1, r11);
    acc8(acc, w2, r20); acc8(acc+8, w2, r21);
    acc8(acc, w3, r30); acc8(acc+8, w3, r31);
  }
  for (; j < deg; ++j) {
    int s = csr[beg+j];
    const uint4* p = (const uint4*)(g1b + (size_t)s*HD) + lane*2;
    uint4 r0 = p[0], r1 = p[1];
    float e = lrelu(as1[s*NH+hg] + adg);
    if (e > m) {
      float sc = __expf(m - e);
      z *= sc;
      #pragma unroll
      for (int i = 0; i < 16; ++i) acc[i] *= sc;
      m = e;
    }
    float w = __expf(e - m);
    z += w;
    acc8(acc, w, r0); acc8(acc+8, w, r1);
  }

  float zinv = 1.f / (z + 1e-16f);
  int cb = lane*16;
  uint o[8];
  #pragma unroll
  for (int q = 0; q < 4; ++q) {
    float4 bv = *(const float4*)&b1[cb + q*4];
    float v0 = fmaxf(acc[q*4+0]*zinv + bv.x, 0.f);
    float v1 = fmaxf(acc[q*4+1]*zinv + bv.y, 0.f);
    float v2 = fmaxf(acc[q*4+2]*zinv + bv.z, 0.f);
    float v3 = fmaxf(acc[q*4+3]*zinv + bv.w, 0.f);
    o[q*2+0] = (unsigned)f2b(v0) | ((unsigned)f2b(v1) << 16);
    o[q*2+1] = (unsigned)f2b(v2) | ((unsigned)f2b(v3) << 16);
  }
  uint4* dst = (uint4*)(hb + (size_t)d*HD) + lane*2;
  dst[0] = make_uint4(o[0], o[1], o[2], o[3]);
  dst[1] = make_uint4(o[4], o[5], o[6], o[7]);
}

// ---------------- GEMM2 (+alpha2 fused): g2 = hrelu @ W2 (bf16, global padded) ----------------
__global__ __launch_bounds__(256) void gemm2_k(const unsigned short* __restrict__ hb,
    const unsigned short* __restrict__ w2b, const float* __restrict__ a2s_g, const float* __restrict__ a2d_g,
    float* __restrict__ g2, float* __restrict__ as2, float* __restrict__ ad2, int N){
  __shared__ float red[3][64][NC+1];         // 14.6 KB
  int t = threadIdx.x, lane = t & 63, wid = t >> 6;
  int n0 = blockIdx.x * 64;
  int n = n0 + lane;
  bool valid = (n < N);
  float acc[NC];
  #pragma unroll
  for (int c = 0; c < NC; ++c) acc[c] = 0.f;
  int k0beg = wid * 256;
  for (int k0 = k0beg; k0 < k0beg + 256; k0 += 8) {
    uint4 raw = valid ? *(const uint4*)(hb + (size_t)n*HD + k0) : make_uint4(0,0,0,0);
    float a[8];
    a[0]=b2f_lo(raw.x); a[1]=b2f_hi(raw.x); a[2]=b2f_lo(raw.y); a[3]=b2f_hi(raw.y);
    a[4]=b2f_lo(raw.z); a[5]=b2f_hi(raw.z); a[6]=b2f_lo(raw.w); a[7]=b2f_hi(raw.w);
    #pragma unroll
    for (int kk = 0; kk < 8; ++kk) {
      const unsigned* wr = (const unsigned*)(w2b + (size_t)(k0 + kk)*NCP);
      uint4 u0 = *(const uint4*)(wr);      // ch 0-7
      uint4 u1 = *(const uint4*)(wr + 4);  // ch 8-15
      unsigned u2 = wr[8];                 // ch 16-17
      float av = a[kk];
      acc[0]  += av * b2f_lo(u0.x); acc[1]  += av * b2f_hi(u0.x);
      acc[2]  += av * b2f_lo(u0.y); acc[3]  += av * b2f_hi(u0.y);
      acc[4]  += av * b2f_lo(u0.z); acc[5]  += av * b2f_hi(u0.z);
      acc[6]  += av * b2f_lo(u0.w); acc[7]  += av * b2f_hi(u0.w);
      acc[8]  += av * b2f_lo(u1.x); acc[9]  += av * b2f_hi(u1.x);
      acc[10] += av * b2f_lo(u1.y); acc[11] += av * b2f_hi(u1.y);
      acc[12] += av * b2f_lo(u1.z); acc[13] += av * b2f_hi(u1.z);
      acc[14] += av * b2f_lo(u1.w); acc[15] += av * b2f_hi(u1.w);
      acc[16] += av * b2f_lo(u2);   acc[17] += av * b2f_hi(u2);
    }
  }
  if (wid > 0) {
    #pragma unroll
    for (int c = 0; c < NC; ++c) red[wid-1][lane][c] = acc[c];
  }
  __syncthreads();
  if (wid == 0 && valid) {
    float tot[NC];
    #pragma unroll
    for (int c = 0; c < NC; ++c)
      tot[c] = acc[c] + red[0][lane][c] + red[1][lane][c] + red[2][lane][c];
    float s = 0.f, dd = 0.f;
    #pragma unroll
    for (int c = 0; c < NC; ++c) {
      s  += tot[c]*a2s_g[c];
      dd += tot[c]*a2d_g[c];
      g2[(size_t)n*NC + c] = tot[c];
    }
    as2[n] = s; ad2[n] = dd;
  }
}

// ---------------- attn2: wave-per-dst single-pass, 3x18-lane edge-parallel ----------------
__global__ __launch_bounds__(256) void attn2_k(const float* __restrict__ g2,
    const float* __restrict__ as2, const float* __restrict__ ad2,
    const int* __restrict__ off, const int* __restrict__ csr,
    const float* __restrict__ b2, float* __restrict__ out, int N){
  int t = threadIdx.x, lane = t & 63, wid = t >> 6;
  int d = blockIdx.x*4 + wid;
  if (d >= N) return;
  int beg = off[d], deg = off[d+1] - beg;
  float adv = ad2[d];
  int g = lane / 18;            // 0..2 active groups, g==3 idle (lanes 54-63)
  int c = lane - g*18;
  float m = -1e30f, z = 0.f, acc = 0.f;
  if (g < 3) {
    int j = g;
    for (; j + 3 < deg; j += 6) {
      int sa = csr[beg+j], sb = csr[beg+j+3];
      float va = g2[(size_t)sa*NC + c];
      float vb = g2[(size_t)sb*NC + c];
      float ea = lrelu(as2[sa] + adv);
      float eb = lrelu(as2[sb] + adv);
      float em = fmaxf(ea, eb);
      if (em > m) { float sc = __expf(m - em); z *= sc; acc *= sc; m = em; }
      float wa = __expf(ea - m), wb = __expf(eb - m);
      z += wa + wb;
      acc += wa*va + wb*vb;
    }
    for (; j < deg; j += 3) {
      int s = csr[beg+j];
      float v = g2[(size_t)s*NC + c];
      float e = lrelu(as2[s] + adv);
      if (e > m) { float sc = __expf(m - e); z *= sc; acc *= sc; m = e; }
      float w = __expf(e - m);
      z += w;
      acc += w*v;
    }
  }
  // merge 3 groups (group 0 always non-empty: deg >= 1 via self-loop)
  float m0 = __shfl(m, 0),  m1 = __shfl(m, 18), m2 = __shfl(m, 36);
  float M  = fmaxf(m0, fmaxf(m1, m2));
  float e0 = __expf(m0 - M), e1 = __expf(m1 - M), e2 = __expf(m2 - M);
  float z0 = __shfl(z, 0),  z1 = __shfl(z, 18), z2 = __shfl(z, 36);
  int cl = (lane < NC) ? lane : 0;
  float a0 = __shfl(acc, cl), a1 = __shfl(acc, cl+18), a2 = __shfl(acc, cl+36);
  if (lane < NC) {
    float Z = z0*e0 + z1*e1 + z2*e2;
    float A = a0*e0 + a1*e1 + a2*e2;
    out[(size_t)d*NC + lane] = A / (Z + 1e-16f) + b2[lane];
  }
}

extern "C" void kernel_launch(void* const* d_in, const int* in_sizes, int n_in,
                              void* d_out, int out_size, void* d_ws, size_t ws_size,
                              hipStream_t stream){
  const float* x   = (const float*)d_in[0];
  const int*   ei  = (const int*)d_in[1];
  const float* W1  = (const float*)d_in[2];
  const float* a1s = (const float*)d_in[3];
  const float* a1d = (const float*)d_in[4];
  const float* b1  = (const float*)d_in[5];
  const float* W2  = (const float*)d_in[6];
  const float* a2s = (const float*)d_in[7];
  const float* a2d = (const float*)d_in[8];
  const float* b2  = (const float*)d_in[9];
  float* out = (float*)d_out;
  int N  = in_sizes[0] / FIN;
  int E0 = in_sizes[1] / 2;
  int Etot = E0 + N;

  // fp32 region
  float* as1 = (float*)d_ws;                 // N*8
  float* ad1 = as1 + (size_t)N*NH;           // N*8
  float* g2  = ad1 + (size_t)N*NH;           // N*18
  float* as2 = g2 + (size_t)N*NC;            // N
  float* ad2 = as2 + N;                      // N
  // bf16 region
  unsigned short* g1b = (unsigned short*)(ad2 + N);       // N*1024
  unsigned short* hb  = g1b + (size_t)N*HD;               // N*1024
  // int region
  int* deg    = (int*)(hb + (size_t)N*HD);
  int* off    = deg + N;
  int* cursor = off + N + 4;   // +4 pad keeps downstream 16B alignment
  int* csr    = cursor + N;
  // bf16 W2 (padded 24) after csr — 16B aligned (verified: offsets are multiples of 16)
  unsigned short* w2b = (unsigned short*)(csr + Etot);    // HD*24
  // converted inputs alias hb (hb written only by attn1, after gemm1 consumed xb/w1t)
  unsigned short* xb  = hb;                   // N*FIN bf16
  unsigned short* w1t = hb + (size_t)N*FIN;   // HD*FIN bf16

  hipMemsetAsync(deg, 0, sizeof(int)*(size_t)N, stream);
  hist_k<<<(Etot+255)/256, 256, 0, stream>>>(ei, E0, N, deg);
  scan_k<<<1, 1024, 0, stream>>>(deg, N, off, cursor);
  scatter_k<<<(Etot+255)/256, 256, 0, stream>>>(ei, E0, N, cursor, csr);

  int total8 = N*FIN/8;
  xcvt_k<<<(total8+255)/256, 256, 0, stream>>>(x, xb, total8);
  w1t_k<<<HD/64, 256, 0, stream>>>(W1, w1t);
  w2cvt_k<<<(HD*NC+255)/256, 256, 0, stream>>>(W2, w2b);

  dim3 g1grid((N+127)/128, HD/128);
  gemm1_mfma_k<<<g1grid, 256, 0, stream>>>(xb, w1t, g1b, N);
  alpha1_k<<<(N+3)/4, 256, 0, stream>>>(g1b, a1s, a1d, as1, ad1, N);
  attn1_k<<<(N+3)/4, 256, 0, stream>>>(g1b, as1, ad1, off, csr, b1, hb, N);
  gemm2_k<<<(N+63)/64, 256, 0, stream>>>(hb, w2b, a2s, a2d, g2, as2, ad2, N);
  attn2_k<<<(N+3)/4, 256, 0, stream>>>(g2, as2, ad2, off, csr, b2, out, N);
}

// Round 6
// 293.184 us; speedup vs baseline: 1.0009x; 1.0009x over previous
//
#include <hip/hip_runtime.h>
#include <math.h>

#define FIN 128
#define NH 8
#define HC 128
#define HD (NH*HC)   // 1024
#define NC 18
#define NCP 24       // W2 row padded to 24 ch (48B, b128-aligned)
#define NEG 0.2f

typedef __attribute__((ext_vector_type(8))) short bf16x8;
typedef __attribute__((ext_vector_type(4))) float f32x4;

__device__ __forceinline__ float lrelu(float v){ return v > 0.f ? v : NEG*v; }

// round-to-nearest-even fp32 -> bf16
__device__ __forceinline__ unsigned short f2b(float f){
  unsigned u = __float_as_uint(f);
  unsigned r = (u + 0x7fffu + ((u >> 16) & 1u)) >> 16;
  return (unsigned short)r;
}
__device__ __forceinline__ float b2f_lo(unsigned u){ return __uint_as_float(u << 16); }
__device__ __forceinline__ float b2f_hi(unsigned u){ return __uint_as_float(u & 0xffff0000u); }

__device__ __forceinline__ void acc8(float* a, float w, uint4 r){
  a[0] += w*b2f_lo(r.x); a[1] += w*b2f_hi(r.x);
  a[2] += w*b2f_lo(r.y); a[3] += w*b2f_hi(r.y);
  a[4] += w*b2f_lo(r.z); a[5] += w*b2f_hi(r.z);
  a[6] += w*b2f_lo(r.w); a[7] += w*b2f_hi(r.w);
}

// ---------------- CSR scan / scatter ----------------
__global__ __launch_bounds__(1024) void scan_k(const int* __restrict__ deg, int N,
                                               int* __restrict__ off, int* __restrict__ cursor){
  __shared__ int wsum[16];
  __shared__ int s_carry;
  int t = threadIdx.x, lane = t & 63, wid = t >> 6;
  if (t == 0) s_carry = 0;
  __syncthreads();
  for (int base = 0; base < N; base += 1024) {
    int i = base + t;
    int v = (i < N) ? deg[i] : 0;
    int x = v;
    #pragma unroll
    for (int o = 1; o < 64; o <<= 1) {
      int y = __shfl_up(x, o, 64);
      if (lane >= o) x += y;
    }
    if (lane == 63) wsum[wid] = x;
    __syncthreads();
    if (wid == 0) {
      int wv = (lane < 16) ? wsum[lane] : 0;
      #pragma unroll
      for (int o = 1; o < 16; o <<= 1) {
        int y = __shfl_up(wv, o, 64);
        if (lane >= o) wv += y;
      }
      if (lane < 16) wsum[lane] = wv;
    }
    __syncthreads();
    int woff = (wid > 0) ? wsum[wid-1] : 0;
    int carry = s_carry;
    int exc = x - v + woff + carry;
    if (i < N) { off[i] = exc; cursor[i] = exc; }
    __syncthreads();
    if (t == 1023) s_carry = carry + wsum[15];
    __syncthreads();
  }
  if (t == 0) off[N] = s_carry;
}

__global__ void scatter_k(const int* __restrict__ ei, int E0, int N,
                          int* __restrict__ cursor, int* __restrict__ csr){
  int e = blockIdx.x*256 + threadIdx.x;
  int tot = E0 + N;
  if (e >= tot) return;
  int src, dst;
  if (e < E0) { src = ei[e]; dst = ei[E0 + e]; }
  else        { src = e - E0; dst = src; }
  int p = atomicAdd(&cursor[dst], 1);
  csr[p] = src;
}

// ---------------- prep: xcvt + w1t + w2cvt + hist in one launch ----------------
__global__ __launch_bounds__(256) void prep_k(const float* __restrict__ x,
    const float* __restrict__ W1, const float* __restrict__ W2,
    const int* __restrict__ ei,
    unsigned short* __restrict__ xb, unsigned short* __restrict__ w1t,
    unsigned short* __restrict__ w2b, int* __restrict__ deg,
    int total8, int bX, int E0, int N, int bH){
  __shared__ unsigned short sT[FIN][64+2];
  int b = blockIdx.x, t = threadIdx.x;
  if (b < bX) {                       // x -> bf16
    int i = b*256 + t;
    if (i < total8) {
      const float4* p = (const float4*)x + (size_t)i*2;
      float4 a = p[0], c = p[1];
      uint4 o;
      o.x = (unsigned)f2b(a.x) | ((unsigned)f2b(a.y) << 16);
      o.y = (unsigned)f2b(a.z) | ((unsigned)f2b(a.w) << 16);
      o.z = (unsigned)f2b(c.x) | ((unsigned)f2b(c.y) << 16);
      o.w = (unsigned)f2b(c.z) | ((unsigned)f2b(c.w) << 16);
      ((uint4*)xb)[i] = o;
    }
    return;
  }
  b -= bX;
  if (b < 16) {                       // W1 -> bf16 transposed [n][k]
    int n0 = b * 64;
    #pragma unroll
    for (int i = 0; i < 32; ++i) {
      int idx = i*256 + t;
      int k = idx >> 6, nl = idx & 63;
      sT[k][nl] = f2b(W1[(size_t)k*HD + n0 + nl]);
    }
    __syncthreads();
    #pragma unroll
    for (int i = 0; i < 16; ++i) {
      int nl = i*4 + (t >> 6);
      int kp = t & 63;
      unsigned u = (unsigned)sT[2*kp][nl] | ((unsigned)sT[2*kp+1][nl] << 16);
      *(unsigned*)&w1t[(size_t)(n0+nl)*FIN + 2*kp] = u;
    }
    return;
  }
  b -= 16;
  if (b < 72) {                       // W2 -> bf16 padded [1024][24]
    int idx = b*256 + t;
    if (idx < HD*NC) {
      int k = idx / NC, c = idx - k*NC;
      w2b[k*NCP + c] = f2b(W2[idx]);
    }
    return;
  }
  b -= 72;
  {                                   // hist
    int e = b*256 + t;
    int tot = E0 + N;
    if (e >= tot) return;
    int dst = (e < E0) ? ei[E0 + e] : (e - E0);
    atomicAdd(&deg[dst], 1);
  }
}

// ---------------- GEMM1 (MFMA bf16) + fused alpha1 + coalesced C-write ----------------
__global__ __launch_bounds__(256) void gemm1_mfma_k(const unsigned short* __restrict__ xb,
    const unsigned short* __restrict__ w1t,
    const float* __restrict__ a1s, const float* __restrict__ a1d,
    unsigned short* __restrict__ g1b, float* __restrict__ as1, float* __restrict__ ad1,
    int N){
  __shared__ unsigned short sA[128][136];  // [m][k] staging, reused as bf16 C tile
  __shared__ unsigned short sB[128][136];  // [n][k]
  __shared__ float sAs[2][128], sAd[2][128];
  int t = threadIdx.x, lane = t & 63, wid = t >> 6;
  int bm = blockIdx.x * 128;
  int head = blockIdx.y;
  int bn = head * 128;
  #pragma unroll
  for (int i = 0; i < 2; ++i) {
    int idx = i*256 + t;
    int row = idx >> 2, seg = idx & 3;
    int gm = bm + row;
    uint4 a0,a1,a2,a3;
    if (gm < N) {
      const uint4* gp = (const uint4*)(xb + (size_t)gm*FIN + seg*32);
      a0 = gp[0]; a1 = gp[1]; a2 = gp[2]; a3 = gp[3];
    } else {
      a0 = a1 = a2 = a3 = make_uint4(0,0,0,0);
    }
    uint4* lp = (uint4*)&sA[row][seg*32];
    lp[0]=a0; lp[1]=a1; lp[2]=a2; lp[3]=a3;
  }
  #pragma unroll
  for (int i = 0; i < 2; ++i) {
    int idx = i*256 + t;
    int row = idx >> 2, seg = idx & 3;
    const uint4* gp = (const uint4*)(w1t + (size_t)(bn + row)*FIN + seg*32);
    uint4* lp = (uint4*)&sB[row][seg*32];
    lp[0]=gp[0]; lp[1]=gp[1]; lp[2]=gp[2]; lp[3]=gp[3];
  }
  __syncthreads();
  int wr = wid >> 1, wc = wid & 1;
  int lr = lane & 15, kb = lane >> 4;
  f32x4 acc[4][4];
  #pragma unroll
  for (int mi = 0; mi < 4; ++mi)
    #pragma unroll
    for (int ni = 0; ni < 4; ++ni) {
      f32x4 z = {0.f, 0.f, 0.f, 0.f};
      acc[mi][ni] = z;
    }
  #pragma unroll
  for (int ks = 0; ks < 4; ++ks) {
    int ko = ks*32 + kb*8;
    bf16x8 a[4], b[4];
    #pragma unroll
    for (int mi = 0; mi < 4; ++mi)
      a[mi] = *(const bf16x8*)&sA[wr*64 + mi*16 + lr][ko];
    #pragma unroll
    for (int ni = 0; ni < 4; ++ni)
      b[ni] = *(const bf16x8*)&sB[wc*64 + ni*16 + lr][ko];
    #pragma unroll
    for (int mi = 0; mi < 4; ++mi)
      #pragma unroll
      for (int ni = 0; ni < 4; ++ni)
        acc[mi][ni] = __builtin_amdgcn_mfma_f32_16x16x32_bf16(a[mi], b[ni], acc[mi][ni], 0, 0, 0);
  }
  __syncthreads();   // MFMA LDS reads complete; sA reusable

  // fused alpha1: per-thread partial over its 4 cols, reduce over 16-lane lr-group
  float a1sv[4], a1dv[4];
  #pragma unroll
  for (int ni = 0; ni < 4; ++ni) {
    int c = wc*64 + ni*16 + lr;
    a1sv[ni] = a1s[head*HC + c];
    a1dv[ni] = a1d[head*HC + c];
  }
  #pragma unroll
  for (int mi = 0; mi < 4; ++mi) {
    #pragma unroll
    for (int r = 0; r < 4; ++r) {
      float ps = acc[mi][0][r]*a1sv[0] + acc[mi][1][r]*a1sv[1]
               + acc[mi][2][r]*a1sv[2] + acc[mi][3][r]*a1sv[3];
      float pd = acc[mi][0][r]*a1dv[0] + acc[mi][1][r]*a1dv[1]
               + acc[mi][2][r]*a1dv[2] + acc[mi][3][r]*a1dv[3];
      #pragma unroll
      for (int o = 1; o < 16; o <<= 1) {
        ps += __shfl_xor(ps, o, 64);
        pd += __shfl_xor(pd, o, 64);
      }
      if (lr == 0) {
        int row = wr*64 + mi*16 + kb*4 + r;
        sAs[wc][row] = ps;
        sAd[wc][row] = pd;
      }
    }
  }
  // stage bf16 C tile in sA for coalesced write
  #pragma unroll
  for (int mi = 0; mi < 4; ++mi)
    #pragma unroll
    for (int ni = 0; ni < 4; ++ni) {
      int col = wc*64 + ni*16 + lr;
      #pragma unroll
      for (int r = 0; r < 4; ++r)
        sA[wr*64 + mi*16 + kb*4 + r][col] = f2b(acc[mi][ni][r]);
    }
  __syncthreads();
  {
    int row = t >> 1, half = t & 1;
    int grow = bm + row;
    if (grow < N) {
      uint4* dst = (uint4*)(g1b + (size_t)grow*HD + bn + half*64);
      const uint4* src = (const uint4*)&sA[row][half*64];
      #pragma unroll
      for (int q = 0; q < 8; ++q) dst[q] = src[q];
    }
    if (t < 128 && bm + t < N) {
      as1[(size_t)(bm + t)*NH + head] = sAs[0][t] + sAs[1][t];
      ad1[(size_t)(bm + t)*NH + head] = sAd[0][t] + sAd[1][t];
    }
  }
}

// ---------------- attn1: wave-per-dst single-pass online softmax + chunk-4 gather ----------------
__global__ __launch_bounds__(256) void attn1_k(const unsigned short* __restrict__ g1b,
    const float* __restrict__ as1, const float* __restrict__ ad1,
    const int* __restrict__ off, const int* __restrict__ csr,
    const float* __restrict__ b1, unsigned short* __restrict__ hb, int N){
  int t = threadIdx.x, lane = t & 63, wid = t >> 6;
  int d = blockIdx.x*4 + wid;
  if (d >= N) return;
  int beg = off[d], deg = off[d+1] - beg;
  int hg = lane >> 3;                 // head for this lane's 16 channels
  float adg = ad1[d*NH + hg];
  float m = -1e30f, z = 0.f;
  float acc[16];
  #pragma unroll
  for (int i = 0; i < 16; ++i) acc[i] = 0.f;

  int j = 0;
  for (; j + 4 <= deg; j += 4) {
    int s0 = csr[beg+j+0], s1 = csr[beg+j+1], s2 = csr[beg+j+2], s3 = csr[beg+j+3];
    const uint4* p0 = (const uint4*)(g1b + (size_t)s0*HD) + lane*2;
    const uint4* p1 = (const uint4*)(g1b + (size_t)s1*HD) + lane*2;
    const uint4* p2 = (const uint4*)(g1b + (size_t)s2*HD) + lane*2;
    const uint4* p3 = (const uint4*)(g1b + (size_t)s3*HD) + lane*2;
    uint4 r00 = p0[0], r01 = p0[1];
    uint4 r10 = p1[0], r11 = p1[1];
    uint4 r20 = p2[0], r21 = p2[1];
    uint4 r30 = p3[0], r31 = p3[1];
    float e0 = lrelu(as1[s0*NH+hg] + adg);
    float e1 = lrelu(as1[s1*NH+hg] + adg);
    float e2 = lrelu(as1[s2*NH+hg] + adg);
    float e3 = lrelu(as1[s3*NH+hg] + adg);
    float em = fmaxf(fmaxf(e0,e1), fmaxf(e2,e3));
    if (em > m) {
      float sc = __expf(m - em);
      z *= sc;
      #pragma unroll
      for (int i = 0; i < 16; ++i) acc[i] *= sc;
      m = em;
    }
    float w0 = __expf(e0 - m), w1 = __expf(e1 - m);
    float w2 = __expf(e2 - m), w3 = __expf(e3 - m);
    z += w0 + w1 + w2 + w3;
    acc8(acc, w0, r00); acc8(acc+8, w0, r01);
    acc8(acc, w1, r10); acc8(acc+8, w1, r11);
    acc8(acc, w2, r20); acc8(acc+8, w2, r21);
    acc8(acc, w3, r30); acc8(acc+8, w3, r31);
  }
  for (; j < deg; ++j) {
    int s = csr[beg+j];
    const uint4* p = (const uint4*)(g1b + (size_t)s*HD) + lane*2;
    uint4 r0 = p[0], r1 = p[1];
    float e = lrelu(as1[s*NH+hg] + adg);
    if (e > m) {
      float sc = __expf(m - e);
      z *= sc;
      #pragma unroll
      for (int i = 0; i < 16; ++i) acc[i] *= sc;
      m = e;
    }
    float w = __expf(e - m);
    z += w;
    acc8(acc, w, r0); acc8(acc+8, w, r1);
  }

  float zinv = 1.f / (z + 1e-16f);
  int cb = lane*16;
  uint o[8];
  #pragma unroll
  for (int q = 0; q < 4; ++q) {
    float4 bv = *(const float4*)&b1[cb + q*4];
    float v0 = fmaxf(acc[q*4+0]*zinv + bv.x, 0.f);
    float v1 = fmaxf(acc[q*4+1]*zinv + bv.y, 0.f);
    float v2 = fmaxf(acc[q*4+2]*zinv + bv.z, 0.f);
    float v3 = fmaxf(acc[q*4+3]*zinv + bv.w, 0.f);
    o[q*2+0] = (unsigned)f2b(v0) | ((unsigned)f2b(v1) << 16);
    o[q*2+1] = (unsigned)f2b(v2) | ((unsigned)f2b(v3) << 16);
  }
  uint4* dst = (uint4*)(hb + (size_t)d*HD) + lane*2;
  dst[0] = make_uint4(o[0], o[1], o[2], o[3]);
  dst[1] = make_uint4(o[4], o[5], o[6], o[7]);
}

// ---------------- GEMM2 (+alpha2 fused): g2 = hrelu @ W2 (bf16, global padded) ----------------
__global__ __launch_bounds__(256) void gemm2_k(const unsigned short* __restrict__ hb,
    const unsigned short* __restrict__ w2b, const float* __restrict__ a2s_g, const float* __restrict__ a2d_g,
    float* __restrict__ g2, float* __restrict__ as2, float* __restrict__ ad2, int N){
  __shared__ float red[3][64][NC+1];
  int t = threadIdx.x, lane = t & 63, wid = t >> 6;
  int n0 = blockIdx.x * 64;
  int n = n0 + lane;
  bool valid = (n < N);
  float acc[NC];
  #pragma unroll
  for (int c = 0; c < NC; ++c) acc[c] = 0.f;
  int k0beg = wid * 256;
  for (int k0 = k0beg; k0 < k0beg + 256; k0 += 8) {
    uint4 raw = valid ? *(const uint4*)(hb + (size_t)n*HD + k0) : make_uint4(0,0,0,0);
    float a[8];
    a[0]=b2f_lo(raw.x); a[1]=b2f_hi(raw.x); a[2]=b2f_lo(raw.y); a[3]=b2f_hi(raw.y);
    a[4]=b2f_lo(raw.z); a[5]=b2f_hi(raw.z); a[6]=b2f_lo(raw.w); a[7]=b2f_hi(raw.w);
    #pragma unroll
    for (int kk = 0; kk < 8; ++kk) {
      const unsigned* wr = (const unsigned*)(w2b + (size_t)(k0 + kk)*NCP);
      uint4 u0 = *(const uint4*)(wr);
      uint4 u1 = *(const uint4*)(wr + 4);
      unsigned u2 = wr[8];
      float av = a[kk];
      acc[0]  += av * b2f_lo(u0.x); acc[1]  += av * b2f_hi(u0.x);
      acc[2]  += av * b2f_lo(u0.y); acc[3]  += av * b2f_hi(u0.y);
      acc[4]  += av * b2f_lo(u0.z); acc[5]  += av * b2f_hi(u0.z);
      acc[6]  += av * b2f_lo(u0.w); acc[7]  += av * b2f_hi(u0.w);
      acc[8]  += av * b2f_lo(u1.x); acc[9]  += av * b2f_hi(u1.x);
      acc[10] += av * b2f_lo(u1.y); acc[11] += av * b2f_hi(u1.y);
      acc[12] += av * b2f_lo(u1.z); acc[13] += av * b2f_hi(u1.z);
      acc[14] += av * b2f_lo(u1.w); acc[15] += av * b2f_hi(u1.w);
      acc[16] += av * b2f_lo(u2);   acc[17] += av * b2f_hi(u2);
    }
  }
  if (wid > 0) {
    #pragma unroll
    for (int c = 0; c < NC; ++c) red[wid-1][lane][c] = acc[c];
  }
  __syncthreads();
  if (wid == 0 && valid) {
    float tot[NC];
    #pragma unroll
    for (int c = 0; c < NC; ++c)
      tot[c] = acc[c] + red[0][lane][c] + red[1][lane][c] + red[2][lane][c];
    float s = 0.f, dd = 0.f;
    #pragma unroll
    for (int c = 0; c < NC; ++c) {
      s  += tot[c]*a2s_g[c];
      dd += tot[c]*a2d_g[c];
      g2[(size_t)n*NC + c] = tot[c];
    }
    as2[n] = s; ad2[n] = dd;
  }
}

// ---------------- attn2: wave-per-dst single-pass, 3x18-lane edge-parallel ----------------
__global__ __launch_bounds__(256) void attn2_k(const float* __restrict__ g2,
    const float* __restrict__ as2, const float* __restrict__ ad2,
    const int* __restrict__ off, const int* __restrict__ csr,
    const float* __restrict__ b2, float* __restrict__ out, int N){
  int t = threadIdx.x, lane = t & 63, wid = t >> 6;
  int d = blockIdx.x*4 + wid;
  if (d >= N) return;
  int beg = off[d], deg = off[d+1] - beg;
  float adv = ad2[d];
  int g = lane / 18;            // 0..2 active groups, g==3 idle
  int c = lane - g*18;
  float m = -1e30f, z = 0.f, acc = 0.f;
  if (g < 3) {
    int j = g;
    for (; j + 3 < deg; j += 6) {
      int sa = csr[beg+j], sb = csr[beg+j+3];
      float va = g2[(size_t)sa*NC + c];
      float vb = g2[(size_t)sb*NC + c];
      float ea = lrelu(as2[sa] + adv);
      float eb = lrelu(as2[sb] + adv);
      float em = fmaxf(ea, eb);
      if (em > m) { float sc = __expf(m - em); z *= sc; acc *= sc; m = em; }
      float wa = __expf(ea - m), wb = __expf(eb - m);
      z += wa + wb;
      acc += wa*va + wb*vb;
    }
    for (; j < deg; j += 3) {
      int s = csr[beg+j];
      float v = g2[(size_t)s*NC + c];
      float e = lrelu(as2[s] + adv);
      if (e > m) { float sc = __expf(m - e); z *= sc; acc *= sc; m = e; }
      float w = __expf(e - m);
      z += w;
      acc += w*v;
    }
  }
  float m0 = __shfl(m, 0),  m1 = __shfl(m, 18), m2 = __shfl(m, 36);
  float M  = fmaxf(m0, fmaxf(m1, m2));
  float e0 = __expf(m0 - M), e1 = __expf(m1 - M), e2 = __expf(m2 - M);
  float z0 = __shfl(z, 0),  z1 = __shfl(z, 18), z2 = __shfl(z, 36);
  int cl = (lane < NC) ? lane : 0;
  float a0 = __shfl(acc, cl), a1 = __shfl(acc, cl+18), a2 = __shfl(acc, cl+36);
  if (lane < NC) {
    float Z = z0*e0 + z1*e1 + z2*e2;
    float A = a0*e0 + a1*e1 + a2*e2;
    out[(size_t)d*NC + lane] = A / (Z + 1e-16f) + b2[lane];
  }
}

extern "C" void kernel_launch(void* const* d_in, const int* in_sizes, int n_in,
                              void* d_out, int out_size, void* d_ws, size_t ws_size,
                              hipStream_t stream){
  const float* x   = (const float*)d_in[0];
  const int*   ei  = (const int*)d_in[1];
  const float* W1  = (const float*)d_in[2];
  const float* a1s = (const float*)d_in[3];
  const float* a1d = (const float*)d_in[4];
  const float* b1  = (const float*)d_in[5];
  const float* W2  = (const float*)d_in[6];
  const float* a2s = (const float*)d_in[7];
  const float* a2d = (const float*)d_in[8];
  const float* b2  = (const float*)d_in[9];
  float* out = (float*)d_out;
  int N  = in_sizes[0] / FIN;
  int E0 = in_sizes[1] / 2;
  int Etot = E0 + N;

  // fp32 region
  float* as1 = (float*)d_ws;                 // N*8
  float* ad1 = as1 + (size_t)N*NH;           // N*8
  float* g2  = ad1 + (size_t)N*NH;           // N*18
  float* as2 = g2 + (size_t)N*NC;            // N
  float* ad2 = as2 + N;                      // N
  // bf16 region
  unsigned short* g1b = (unsigned short*)(ad2 + N);       // N*1024
  unsigned short* hb  = g1b + (size_t)N*HD;               // N*1024
  // int region
  int* deg    = (int*)(hb + (size_t)N*HD);
  int* off    = deg + N;
  int* cursor = off + N + 4;   // +4 pad keeps downstream 16B alignment
  int* csr    = cursor + N;
  // bf16 W2 (padded 24) after csr
  unsigned short* w2b = (unsigned short*)(csr + Etot);    // HD*24
  // converted inputs alias hb (hb written only by attn1, after gemm1 consumed xb/w1t)
  unsigned short* xb  = hb;                   // N*FIN bf16
  unsigned short* w1t = hb + (size_t)N*FIN;   // HD*FIN bf16

  hipMemsetAsync(deg, 0, sizeof(int)*(size_t)N, stream);

  int total8 = N*FIN/8;
  int bX = (total8 + 255)/256;
  int bH = (Etot + 255)/256;
  prep_k<<<bX + 16 + 72 + bH, 256, 0, stream>>>(x, W1, W2, ei, xb, w1t, w2b, deg,
                                                total8, bX, E0, N, bH);
  scan_k<<<1, 1024, 0, stream>>>(deg, N, off, cursor);
  scatter_k<<<(Etot+255)/256, 256, 0, stream>>>(ei, E0, N, cursor, csr);

  dim3 g1grid((N+127)/128, HD/128);
  gemm1_mfma_k<<<g1grid, 256, 0, stream>>>(xb, w1t, a1s, a1d, g1b, as1, ad1, N);
  attn1_k<<<(N+3)/4, 256, 0, stream>>>(g1b, as1, ad1, off, csr, b1, hb, N);
  gemm2_k<<<(N+63)/64, 256, 0, stream>>>(hb, w2b, a2s, a2d, g2, as2, ad2, N);
  attn2_k<<<(N+3)/4, 256, 0, stream>>>(g2, as2, ad2, off, csr, b2, out, N);
}

// Round 7
// 265.410 us; speedup vs baseline: 1.1056x; 1.1046x over previous
//
#include <hip/hip_runtime.h>
#include <math.h>

#define FIN 128
#define NH 8
#define HC 128
#define HD (NH*HC)   // 1024
#define NC 18
#define NW2 32       // w2t padded rows (classes), 32 for 2 n-tiles
#define NEG 0.2f

typedef __attribute__((ext_vector_type(8))) short bf16x8;
typedef __attribute__((ext_vector_type(4))) float f32x4;

__device__ __forceinline__ float lrelu(float v){ return v > 0.f ? v : NEG*v; }

// round-to-nearest-even fp32 -> bf16
__device__ __forceinline__ unsigned short f2b(float f){
  unsigned u = __float_as_uint(f);
  unsigned r = (u + 0x7fffu + ((u >> 16) & 1u)) >> 16;
  return (unsigned short)r;
}
__device__ __forceinline__ float b2f_lo(unsigned u){ return __uint_as_float(u << 16); }
__device__ __forceinline__ float b2f_hi(unsigned u){ return __uint_as_float(u & 0xffff0000u); }

__device__ __forceinline__ void acc8(float* a, float w, uint4 r){
  a[0] += w*b2f_lo(r.x); a[1] += w*b2f_hi(r.x);
  a[2] += w*b2f_lo(r.y); a[3] += w*b2f_hi(r.y);
  a[4] += w*b2f_lo(r.z); a[5] += w*b2f_hi(r.z);
  a[6] += w*b2f_lo(r.w); a[7] += w*b2f_hi(r.w);
}

// ---------------- scan: thread-serial 2-pass, single barrier round ----------------
__global__ __launch_bounds__(1024) void scan_k(const int* __restrict__ deg, int N,
                                               int* __restrict__ off, int* __restrict__ cursor){
  __shared__ int wsum[16];
  int t = threadIdx.x, lane = t & 63, wid = t >> 6;
  int PER = (N + 1023) >> 10;
  int base = t * PER;
  int sum = 0;
  for (int i = 0; i < PER; ++i) {
    int idx = base + i;
    if (idx < N) sum += deg[idx];
  }
  // wave inclusive scan of per-thread sums
  int x = sum;
  #pragma unroll
  for (int o = 1; o < 64; o <<= 1) {
    int y = __shfl_up(x, o, 64);
    if (lane >= o) x += y;
  }
  if (lane == 63) wsum[wid] = x;
  __syncthreads();
  if (wid == 0 && lane < 16) {
    int wv = wsum[lane];
    #pragma unroll
    for (int o = 1; o < 16; o <<= 1) {
      int y = __shfl_up(wv, o, 16);
      if (lane >= o) wv += y;
    }
    wsum[lane] = wv;
  }
  __syncthreads();
  int carry = x - sum + (wid > 0 ? wsum[wid-1] : 0);
  int run = carry;
  for (int i = 0; i < PER; ++i) {
    int idx = base + i;
    if (idx < N) {
      off[idx] = run; cursor[idx] = run;
      run += deg[idx];
    }
  }
  if (base < N && base + PER >= N) off[N] = run;
}

__global__ void scatter_k(const int* __restrict__ ei, int E0, int N,
                          int* __restrict__ cursor, int* __restrict__ csr){
  int e = blockIdx.x*256 + threadIdx.x;
  int tot = E0 + N;
  if (e >= tot) return;
  int src, dst;
  if (e < E0) { src = ei[e]; dst = ei[E0 + e]; }
  else        { src = e - E0; dst = src; }
  int p = atomicAdd(&cursor[dst], 1);
  csr[p] = src;
}

// ---------------- prep: xcvt + w1t + w2t + hist in one launch ----------------
__global__ __launch_bounds__(256) void prep_k(const float* __restrict__ x,
    const float* __restrict__ W1, const float* __restrict__ W2,
    const int* __restrict__ ei,
    unsigned short* __restrict__ xb, unsigned short* __restrict__ w1t,
    unsigned short* __restrict__ w2t, int* __restrict__ deg,
    int total8, int bX, int E0, int N){
  __shared__ unsigned short sT[FIN][64+2];
  int b = blockIdx.x, t = threadIdx.x;
  if (b < bX) {                       // x -> bf16
    int i = b*256 + t;
    if (i < total8) {
      const float4* p = (const float4*)x + (size_t)i*2;
      float4 a = p[0], c = p[1];
      uint4 o;
      o.x = (unsigned)f2b(a.x) | ((unsigned)f2b(a.y) << 16);
      o.y = (unsigned)f2b(a.z) | ((unsigned)f2b(a.w) << 16);
      o.z = (unsigned)f2b(c.x) | ((unsigned)f2b(c.y) << 16);
      o.w = (unsigned)f2b(c.z) | ((unsigned)f2b(c.w) << 16);
      ((uint4*)xb)[i] = o;
    }
    return;
  }
  b -= bX;
  if (b < 16) {                       // W1 -> bf16 transposed [n][k]
    int n0 = b * 64;
    #pragma unroll
    for (int i = 0; i < 32; ++i) {
      int idx = i*256 + t;
      int k = idx >> 6, nl = idx & 63;
      sT[k][nl] = f2b(W1[(size_t)k*HD + n0 + nl]);
    }
    __syncthreads();
    #pragma unroll
    for (int i = 0; i < 16; ++i) {
      int nl = i*4 + (t >> 6);
      int kp = t & 63;
      unsigned u = (unsigned)sT[2*kp][nl] | ((unsigned)sT[2*kp+1][nl] << 16);
      *(unsigned*)&w1t[(size_t)(n0+nl)*FIN + 2*kp] = u;
    }
    return;
  }
  b -= 16;
  if (b < (NW2*HD)/256) {             // W2 -> bf16 transposed padded [32][1024]
    int idx = b*256 + t;
    int n = idx >> 10, k = idx & 1023;
    w2t[idx] = (n < NC) ? f2b(W2[(size_t)k*NC + n]) : (unsigned short)0;
    return;
  }
  b -= (NW2*HD)/256;
  {                                   // hist
    int e = b*256 + t;
    int tot = E0 + N;
    if (e >= tot) return;
    int dst = (e < E0) ? ei[E0 + e] : (e - E0);
    atomicAdd(&deg[dst], 1);
  }
}

// ---------------- GEMM1 (MFMA bf16) + fused alpha1 + coalesced C-write ----------------
__global__ __launch_bounds__(256) void gemm1_mfma_k(const unsigned short* __restrict__ xb,
    const unsigned short* __restrict__ w1t,
    const float* __restrict__ a1s, const float* __restrict__ a1d,
    unsigned short* __restrict__ g1b, float* __restrict__ as1, float* __restrict__ ad1,
    int N){
  __shared__ unsigned short sA[128][136];  // [m][k] staging, reused as bf16 C tile
  __shared__ unsigned short sB[128][136];  // [n][k]
  __shared__ float sAs[2][128], sAd[2][128];
  int t = threadIdx.x, lane = t & 63, wid = t >> 6;
  int bm = blockIdx.x * 128;
  int head = blockIdx.y;
  int bn = head * 128;
  #pragma unroll
  for (int i = 0; i < 2; ++i) {
    int idx = i*256 + t;
    int row = idx >> 2, seg = idx & 3;
    int gm = bm + row;
    uint4 a0,a1,a2,a3;
    if (gm < N) {
      const uint4* gp = (const uint4*)(xb + (size_t)gm*FIN + seg*32);
      a0 = gp[0]; a1 = gp[1]; a2 = gp[2]; a3 = gp[3];
    } else {
      a0 = a1 = a2 = a3 = make_uint4(0,0,0,0);
    }
    uint4* lp = (uint4*)&sA[row][seg*32];
    lp[0]=a0; lp[1]=a1; lp[2]=a2; lp[3]=a3;
  }
  #pragma unroll
  for (int i = 0; i < 2; ++i) {
    int idx = i*256 + t;
    int row = idx >> 2, seg = idx & 3;
    const uint4* gp = (const uint4*)(w1t + (size_t)(bn + row)*FIN + seg*32);
    uint4* lp = (uint4*)&sB[row][seg*32];
    lp[0]=gp[0]; lp[1]=gp[1]; lp[2]=gp[2]; lp[3]=gp[3];
  }
  __syncthreads();
  int wr = wid >> 1, wc = wid & 1;
  int lr = lane & 15, kb = lane >> 4;
  f32x4 acc[4][4];
  #pragma unroll
  for (int mi = 0; mi < 4; ++mi)
    #pragma unroll
    for (int ni = 0; ni < 4; ++ni) {
      f32x4 z = {0.f, 0.f, 0.f, 0.f};
      acc[mi][ni] = z;
    }
  #pragma unroll
  for (int ks = 0; ks < 4; ++ks) {
    int ko = ks*32 + kb*8;
    bf16x8 a[4], b[4];
    #pragma unroll
    for (int mi = 0; mi < 4; ++mi)
      a[mi] = *(const bf16x8*)&sA[wr*64 + mi*16 + lr][ko];
    #pragma unroll
    for (int ni = 0; ni < 4; ++ni)
      b[ni] = *(const bf16x8*)&sB[wc*64 + ni*16 + lr][ko];
    #pragma unroll
    for (int mi = 0; mi < 4; ++mi)
      #pragma unroll
      for (int ni = 0; ni < 4; ++ni)
        acc[mi][ni] = __builtin_amdgcn_mfma_f32_16x16x32_bf16(a[mi], b[ni], acc[mi][ni], 0, 0, 0);
  }
  __syncthreads();   // MFMA LDS reads complete; sA reusable

  // fused alpha1
  float a1sv[4], a1dv[4];
  #pragma unroll
  for (int ni = 0; ni < 4; ++ni) {
    int c = wc*64 + ni*16 + lr;
    a1sv[ni] = a1s[head*HC + c];
    a1dv[ni] = a1d[head*HC + c];
  }
  #pragma unroll
  for (int mi = 0; mi < 4; ++mi) {
    #pragma unroll
    for (int r = 0; r < 4; ++r) {
      float ps = acc[mi][0][r]*a1sv[0] + acc[mi][1][r]*a1sv[1]
               + acc[mi][2][r]*a1sv[2] + acc[mi][3][r]*a1sv[3];
      float pd = acc[mi][0][r]*a1dv[0] + acc[mi][1][r]*a1dv[1]
               + acc[mi][2][r]*a1dv[2] + acc[mi][3][r]*a1dv[3];
      #pragma unroll
      for (int o = 1; o < 16; o <<= 1) {
        ps += __shfl_xor(ps, o, 64);
        pd += __shfl_xor(pd, o, 64);
      }
      if (lr == 0) {
        int row = wr*64 + mi*16 + kb*4 + r;
        sAs[wc][row] = ps;
        sAd[wc][row] = pd;
      }
    }
  }
  // stage bf16 C tile for coalesced write
  #pragma unroll
  for (int mi = 0; mi < 4; ++mi)
    #pragma unroll
    for (int ni = 0; ni < 4; ++ni) {
      int col = wc*64 + ni*16 + lr;
      #pragma unroll
      for (int r = 0; r < 4; ++r)
        sA[wr*64 + mi*16 + kb*4 + r][col] = f2b(acc[mi][ni][r]);
    }
  __syncthreads();
  {
    int row = t >> 1, half = t & 1;
    int grow = bm + row;
    if (grow < N) {
      uint4* dst = (uint4*)(g1b + (size_t)grow*HD + bn + half*64);
      const uint4* src = (const uint4*)&sA[row][half*64];
      #pragma unroll
      for (int q = 0; q < 8; ++q) dst[q] = src[q];
    }
    if (t < 128 && bm + t < N) {
      as1[(size_t)(bm + t)*NH + head] = sAs[0][t] + sAs[1][t];
      ad1[(size_t)(bm + t)*NH + head] = sAd[0][t] + sAd[1][t];
    }
  }
}

// ---------------- attn1: wave-per-dst single-pass online softmax + chunk-4 gather ----------------
__global__ __launch_bounds__(256) void attn1_k(const unsigned short* __restrict__ g1b,
    const float* __restrict__ as1, const float* __restrict__ ad1,
    const int* __restrict__ off, const int* __restrict__ csr,
    const float* __restrict__ b1, unsigned short* __restrict__ hb, int N){
  int t = threadIdx.x, lane = t & 63, wid = t >> 6;
  int d = blockIdx.x*4 + wid;
  if (d >= N) return;
  int beg = off[d], deg = off[d+1] - beg;
  int hg = lane >> 3;
  float adg = ad1[d*NH + hg];
  float m = -1e30f, z = 0.f;
  float acc[16];
  #pragma unroll
  for (int i = 0; i < 16; ++i) acc[i] = 0.f;

  int j = 0;
  for (; j + 4 <= deg; j += 4) {
    int s0 = csr[beg+j+0], s1 = csr[beg+j+1], s2 = csr[beg+j+2], s3 = csr[beg+j+3];
    const uint4* p0 = (const uint4*)(g1b + (size_t)s0*HD) + lane*2;
    const uint4* p1 = (const uint4*)(g1b + (size_t)s1*HD) + lane*2;
    const uint4* p2 = (const uint4*)(g1b + (size_t)s2*HD) + lane*2;
    const uint4* p3 = (const uint4*)(g1b + (size_t)s3*HD) + lane*2;
    uint4 r00 = p0[0], r01 = p0[1];
    uint4 r10 = p1[0], r11 = p1[1];
    uint4 r20 = p2[0], r21 = p2[1];
    uint4 r30 = p3[0], r31 = p3[1];
    float e0 = lrelu(as1[s0*NH+hg] + adg);
    float e1 = lrelu(as1[s1*NH+hg] + adg);
    float e2 = lrelu(as1[s2*NH+hg] + adg);
    float e3 = lrelu(as1[s3*NH+hg] + adg);
    float em = fmaxf(fmaxf(e0,e1), fmaxf(e2,e3));
    if (em > m) {
      float sc = __expf(m - em);
      z *= sc;
      #pragma unroll
      for (int i = 0; i < 16; ++i) acc[i] *= sc;
      m = em;
    }
    float w0 = __expf(e0 - m), w1 = __expf(e1 - m);
    float w2 = __expf(e2 - m), w3 = __expf(e3 - m);
    z += w0 + w1 + w2 + w3;
    acc8(acc, w0, r00); acc8(acc+8, w0, r01);
    acc8(acc, w1, r10); acc8(acc+8, w1, r11);
    acc8(acc, w2, r20); acc8(acc+8, w2, r21);
    acc8(acc, w3, r30); acc8(acc+8, w3, r31);
  }
  for (; j < deg; ++j) {
    int s = csr[beg+j];
    const uint4* p = (const uint4*)(g1b + (size_t)s*HD) + lane*2;
    uint4 r0 = p[0], r1 = p[1];
    float e = lrelu(as1[s*NH+hg] + adg);
    if (e > m) {
      float sc = __expf(m - e);
      z *= sc;
      #pragma unroll
      for (int i = 0; i < 16; ++i) acc[i] *= sc;
      m = e;
    }
    float w = __expf(e - m);
    z += w;
    acc8(acc, w, r0); acc8(acc+8, w, r1);
  }

  float zinv = 1.f / (z + 1e-16f);
  int cb = lane*16;
  uint o[8];
  #pragma unroll
  for (int q = 0; q < 4; ++q) {
    float4 bv = *(const float4*)&b1[cb + q*4];
    float v0 = fmaxf(acc[q*4+0]*zinv + bv.x, 0.f);
    float v1 = fmaxf(acc[q*4+1]*zinv + bv.y, 0.f);
    float v2 = fmaxf(acc[q*4+2]*zinv + bv.z, 0.f);
    float v3 = fmaxf(acc[q*4+3]*zinv + bv.w, 0.f);
    o[q*2+0] = (unsigned)f2b(v0) | ((unsigned)f2b(v1) << 16);
    o[q*2+1] = (unsigned)f2b(v2) | ((unsigned)f2b(v3) << 16);
  }
  uint4* dst = (uint4*)(hb + (size_t)d*HD) + lane*2;
  dst[0] = make_uint4(o[0], o[1], o[2], o[3]);
  dst[1] = make_uint4(o[4], o[5], o[6], o[7]);
}

// ---------------- GEMM2 (MFMA) + fused alpha2: 32-row tiles, K-split 4 waves ----------------
__global__ __launch_bounds__(256) void gemm2_k(const unsigned short* __restrict__ hb,
    const unsigned short* __restrict__ w2t, const float* __restrict__ a2s_g, const float* __restrict__ a2d_g,
    float* __restrict__ g2, float* __restrict__ as2, float* __restrict__ ad2, int N){
  __shared__ float red[4][32][32];   // 16 KB
  int t = threadIdx.x, lane = t & 63, wid = t >> 6;
  int bm = blockIdx.x * 32;
  int lr = lane & 15, kb = lane >> 4;
  int kw = wid * 256;
  f32x4 acc[2][2];
  #pragma unroll
  for (int mi = 0; mi < 2; ++mi)
    #pragma unroll
    for (int ni = 0; ni < 2; ++ni) {
      f32x4 z = {0.f,0.f,0.f,0.f};
      acc[mi][ni] = z;
    }
  bf16x8 zf;
  #pragma unroll
  for (int q = 0; q < 8; ++q) zf[q] = 0;
  int r0n = bm + lr, r1n = bm + 16 + lr;
  #pragma unroll
  for (int ks = 0; ks < 8; ++ks) {
    int k = kw + ks*32 + kb*8;
    bf16x8 a0 = (r0n < N) ? *(const bf16x8*)&hb[(size_t)r0n*HD + k] : zf;
    bf16x8 a1 = (r1n < N) ? *(const bf16x8*)&hb[(size_t)r1n*HD + k] : zf;
    bf16x8 b0 = *(const bf16x8*)&w2t[(size_t)lr*HD + k];
    bf16x8 b1 = *(const bf16x8*)&w2t[(size_t)(16+lr)*HD + k];
    acc[0][0] = __builtin_amdgcn_mfma_f32_16x16x32_bf16(a0, b0, acc[0][0], 0,0,0);
    acc[0][1] = __builtin_amdgcn_mfma_f32_16x16x32_bf16(a0, b1, acc[0][1], 0,0,0);
    acc[1][0] = __builtin_amdgcn_mfma_f32_16x16x32_bf16(a1, b0, acc[1][0], 0,0,0);
    acc[1][1] = __builtin_amdgcn_mfma_f32_16x16x32_bf16(a1, b1, acc[1][1], 0,0,0);
  }
  #pragma unroll
  for (int mi = 0; mi < 2; ++mi)
    #pragma unroll
    for (int ni = 0; ni < 2; ++ni)
      #pragma unroll
      for (int r = 0; r < 4; ++r)
        red[wid][mi*16 + kb*4 + r][ni*16 + lr] = acc[mi][ni][r];
  __syncthreads();
  // final: 32x32 cells, 4 per thread
  int row = t >> 3;
  int c4 = (t & 7) * 4;
  float tot[4];
  #pragma unroll
  for (int q = 0; q < 4; ++q)
    tot[q] = red[0][row][c4+q] + red[1][row][c4+q] + red[2][row][c4+q] + red[3][row][c4+q];
  int n = bm + row;
  float ps = 0.f, pd = 0.f;
  #pragma unroll
  for (int q = 0; q < 4; ++q) {
    int c = c4 + q;
    if (c < NC) {
      ps += tot[q]*a2s_g[c];
      pd += tot[q]*a2d_g[c];
    }
  }
  #pragma unroll
  for (int o = 1; o < 8; o <<= 1) {
    ps += __shfl_xor(ps, o, 8);
    pd += __shfl_xor(pd, o, 8);
  }
  if (n < N) {
    #pragma unroll
    for (int q = 0; q < 4; ++q) {
      int c = c4 + q;
      if (c < NC) g2[(size_t)n*NC + c] = tot[q];
    }
    if ((t & 7) == 0) { as2[n] = ps; ad2[n] = pd; }
  }
}

// ---------------- attn2: wave-per-dst single-pass, 3x18-lane edge-parallel ----------------
__global__ __launch_bounds__(256) void attn2_k(const float* __restrict__ g2,
    const float* __restrict__ as2, const float* __restrict__ ad2,
    const int* __restrict__ off, const int* __restrict__ csr,
    const float* __restrict__ b2, float* __restrict__ out, int N){
  int t = threadIdx.x, lane = t & 63, wid = t >> 6;
  int d = blockIdx.x*4 + wid;
  if (d >= N) return;
  int beg = off[d], deg = off[d+1] - beg;
  float adv = ad2[d];
  int g = lane / 18;            // 0..2 active groups, g==3 idle
  int c = lane - g*18;
  float m = -1e30f, z = 0.f, acc = 0.f;
  if (g < 3) {
    int j = g;
    for (; j + 3 < deg; j += 6) {
      int sa = csr[beg+j], sb = csr[beg+j+3];
      float va = g2[(size_t)sa*NC + c];
      float vb = g2[(size_t)sb*NC + c];
      float ea = lrelu(as2[sa] + adv);
      float eb = lrelu(as2[sb] + adv);
      float em = fmaxf(ea, eb);
      if (em > m) { float sc = __expf(m - em); z *= sc; acc *= sc; m = em; }
      float wa = __expf(ea - m), wb = __expf(eb - m);
      z += wa + wb;
      acc += wa*va + wb*vb;
    }
    for (; j < deg; j += 3) {
      int s = csr[beg+j];
      float v = g2[(size_t)s*NC + c];
      float e = lrelu(as2[s] + adv);
      if (e > m) { float sc = __expf(m - e); z *= sc; acc *= sc; m = e; }
      float w = __expf(e - m);
      z += w;
      acc += w*v;
    }
  }
  float m0 = __shfl(m, 0),  m1 = __shfl(m, 18), m2 = __shfl(m, 36);
  float M  = fmaxf(m0, fmaxf(m1, m2));
  float e0 = __expf(m0 - M), e1 = __expf(m1 - M), e2 = __expf(m2 - M);
  float z0 = __shfl(z, 0),  z1 = __shfl(z, 18), z2 = __shfl(z, 36);
  int cl = (lane < NC) ? lane : 0;
  float a0 = __shfl(acc, cl), a1 = __shfl(acc, cl+18), a2 = __shfl(acc, cl+36);
  if (lane < NC) {
    float Z = z0*e0 + z1*e1 + z2*e2;
    float A = a0*e0 + a1*e1 + a2*e2;
    out[(size_t)d*NC + lane] = A / (Z + 1e-16f) + b2[lane];
  }
}

extern "C" void kernel_launch(void* const* d_in, const int* in_sizes, int n_in,
                              void* d_out, int out_size, void* d_ws, size_t ws_size,
                              hipStream_t stream){
  const float* x   = (const float*)d_in[0];
  const int*   ei  = (const int*)d_in[1];
  const float* W1  = (const float*)d_in[2];
  const float* a1s = (const float*)d_in[3];
  const float* a1d = (const float*)d_in[4];
  const float* b1  = (const float*)d_in[5];
  const float* W2  = (const float*)d_in[6];
  const float* a2s = (const float*)d_in[7];
  const float* a2d = (const float*)d_in[8];
  const float* b2  = (const float*)d_in[9];
  float* out = (float*)d_out;
  int N  = in_sizes[0] / FIN;
  int E0 = in_sizes[1] / 2;
  int Etot = E0 + N;

  // fp32 region
  float* as1 = (float*)d_ws;                 // N*8
  float* ad1 = as1 + (size_t)N*NH;           // N*8
  float* g2  = ad1 + (size_t)N*NH;           // N*18
  float* as2 = g2 + (size_t)N*NC;            // N
  float* ad2 = as2 + N;                      // N
  // bf16 region
  unsigned short* g1b = (unsigned short*)(ad2 + N);       // N*1024
  unsigned short* hb  = g1b + (size_t)N*HD;               // N*1024
  // int region
  int* deg    = (int*)(hb + (size_t)N*HD);
  int* off    = deg + N;
  int* cursor = off + N + 4;   // +4 pad keeps downstream 16B alignment
  int* csr    = cursor + N;
  // bf16 W2 transposed padded [32][1024] after csr (16B-aligned)
  unsigned short* w2t = (unsigned short*)(csr + Etot);    // 32*1024
  // converted inputs alias hb (hb written only by attn1, after gemm1 consumed xb/w1t)
  unsigned short* xb  = hb;                   // N*FIN bf16
  unsigned short* w1t = hb + (size_t)N*FIN;   // HD*FIN bf16

  hipMemsetAsync(deg, 0, sizeof(int)*(size_t)N, stream);

  int total8 = N*FIN/8;
  int bX = (total8 + 255)/256;
  int bH = (Etot + 255)/256;
  int bW2 = (NW2*HD)/256;   // 128
  prep_k<<<bX + 16 + bW2 + bH, 256, 0, stream>>>(x, W1, W2, ei, xb, w1t, w2t, deg,
                                                 total8, bX, E0, N);
  scan_k<<<1, 1024, 0, stream>>>(deg, N, off, cursor);
  scatter_k<<<(Etot+255)/256, 256, 0, stream>>>(ei, E0, N, cursor, csr);

  dim3 g1grid((N+127)/128, HD/128);
  gemm1_mfma_k<<<g1grid, 256, 0, stream>>>(xb, w1t, a1s, a1d, g1b, as1, ad1, N);
  attn1_k<<<(N+3)/4, 256, 0, stream>>>(g1b, as1, ad1, off, csr, b1, hb, N);
  gemm2_k<<<(N+31)/32, 256, 0, stream>>>(hb, w2t, a2s, a2d, g2, as2, ad2, N);
  attn2_k<<<(N+3)/4, 256, 0, stream>>>(g2, as2, ad2, off, csr, b2, out, N);
}